// Round 17
// baseline (159.190 us; speedup 1.0000x reference)
//
#include <hip/hip_runtime.h>
#include <hip/hip_bf16.h>

typedef __attribute__((ext_vector_type(8))) short short8;
typedef __attribute__((ext_vector_type(4))) float f32x4;
typedef __attribute__((ext_vector_type(4))) unsigned uint4v;

#define LOG2E 1.4426950408889634f
#define ILN2SQ 0.4804530139182014f   // (ln2)^2, compensates LOG2E^2 in relu^2 path

// compiler emits v_cvt_pk_bf16_f32 for this (m240: do NOT hand-write the asm)
__device__ __forceinline__ unsigned packbf2(float a, float b) {
  __hip_bfloat162 h = __float22bfloat162_rn(make_float2(a, b));
  return *reinterpret_cast<unsigned*>(&h);
}
// XOR swizzle spreading 16B chunks across banks; bits 4..6 only (within 128B row)
__device__ __forceinline__ int swz(int row) {
  return ((row & 7) << 4) ^ (((row >> 3) & 3) << 5);
}
__device__ __forceinline__ void gload16(const void* g, void* l) {
  __builtin_amdgcn_global_load_lds(
      (const __attribute__((address_space(1))) unsigned int*)g,
      (__attribute__((address_space(3))) unsigned int*)l, 16, 0, 0);
}

// PV key permutation: logical slot p (0..63) within a V^T row maps to physical key
//   R = p>>5, g = (p&31)>>3, jj = p&7  ->  key = (R*2 + (jj>>2))*16 + g*4 + (jj&3)
// so that lane-group g's 16B fragment read delivers keys matching the lane's own
// QK^T accumulator scores (B-frag = concat of packed acc, no shuffles).
__device__ __forceinline__ int pv_key(int p) {
  const int R = p >> 5, g = (p & 31) >> 3, jj = p & 7;
  return (R * 2 + (jj >> 2)) * 16 + g * 4 + (jj & 3);
}

// ---------------- prep: fp32 -> bf16, pre-swizzled global layouts ----------------
// KP  = ws[0..8MB):   [bh][s][128B]      bf16 K rows, 16B chunks XOR-swz by s
// VTP = ws[8MB..16MB): [bh][t][e][128B]  bf16 V^T tiles, PV-KEY-PERMUTED within row
//        (byte pos 2*p holds V[pv_key(p)][e]); XOR-swz by e.
__global__ __launch_bounds__(256) void assa_prep(
    const float* __restrict__ K, const float* __restrict__ V, char* __restrict__ WS)
{
  constexpr int L = 2048, RS = 1024, E = 64;
  char* KP = WS;
  char* VTP = WS + (size_t)8 * 1024 * 1024;
  __shared__ float tile[64][65];
  const int tid = threadIdx.x;

  if (blockIdx.x < 1024) {
    // ---- K path: thread = quarter row (16 floats) ----
    const int gid = blockIdx.x * 256 + tid;
    const int rid = gid >> 2;            // bh*2048 + s
    const int e0 = (gid & 3) * 16;
    const int bh = rid >> 11, s = rid & 2047;
    const int b = bh >> 4, h = bh & 15;
    const float* kr = K + ((size_t)b * L + s) * RS + h * E + e0;
    const float4 u0 = *(const float4*)(kr);
    const float4 u1 = *(const float4*)(kr + 4);
    const float4 u2 = *(const float4*)(kr + 8);
    const float4 u3 = *(const float4*)(kr + 12);
    uint4v w0, w1;
    w0[0] = packbf2(u0.x, u0.y); w0[1] = packbf2(u0.z, u0.w);
    w0[2] = packbf2(u1.x, u1.y); w0[3] = packbf2(u1.z, u1.w);
    w1[0] = packbf2(u2.x, u2.y); w1[1] = packbf2(u2.z, u2.w);
    w1[2] = packbf2(u3.x, u3.y); w1[3] = packbf2(u3.z, u3.w);
    char* dst = KP + (size_t)rid * 128;
    const int sz = swz(s);
    *(uint4v*)(dst + ((e0 * 2) ^ sz)) = w0;
    *(uint4v*)(dst + ((e0 * 2 + 16) ^ sz)) = w1;
  } else {
    // ---- V path: block = (bh, t); transpose 64x64 via LDS, pv_key-permuted write ----
    const int bx = blockIdx.x - 1024;
    const int bh = bx >> 5, t5 = bx & 31;
    const int b = bh >> 4, h = bh & 15;
    const float* vb = V + ((size_t)b * L + t5 * 64) * RS + h * E;
    {
      const int key = tid >> 2, e0 = (tid & 3) * 16;
      const float* vr = vb + (size_t)key * RS + e0;
      const float4 u0 = *(const float4*)(vr);
      const float4 u1 = *(const float4*)(vr + 4);
      const float4 u2 = *(const float4*)(vr + 8);
      const float4 u3 = *(const float4*)(vr + 12);
      float* tr = &tile[key][e0];
      tr[0] = u0.x; tr[1] = u0.y; tr[2] = u0.z; tr[3] = u0.w;
      tr[4] = u1.x; tr[5] = u1.y; tr[6] = u1.z; tr[7] = u1.w;
      tr[8] = u2.x; tr[9] = u2.y; tr[10] = u2.z; tr[11] = u2.w;
      tr[12] = u3.x; tr[13] = u3.y; tr[14] = u3.z; tr[15] = u3.w;
    }
    __syncthreads();
    const int e = tid >> 2, p0 = (tid & 3) * 16;   // positions p0..p0+15
    uint4v w0, w1;
    #pragma unroll
    for (int i = 0; i < 4; ++i)
      w0[i] = packbf2(tile[pv_key(p0 + 2 * i)][e], tile[pv_key(p0 + 2 * i + 1)][e]);
    #pragma unroll
    for (int i = 0; i < 4; ++i)
      w1[i] = packbf2(tile[pv_key(p0 + 8 + 2 * i)][e], tile[pv_key(p0 + 9 + 2 * i)][e]);
    char* dst = VTP + ((size_t)bx * 64 + e) * 128;
    const int sz = swz(e);
    *(uint4v*)(dst + ((p0 * 2) ^ sz)) = w0;
    *(uint4v*)(dst + ((p0 * 2 + 16) ^ sz)) = w1;
  }
}

// -------- main fused: QBLK=128, 8 waves x 16 q-rows, KVBLK=128 (2 subtiles) --------
__global__ __launch_bounds__(512, 4) void assa_fused(
    const float* __restrict__ Q, const char* __restrict__ WS,
    const float* __restrict__ A1, const float* __restrict__ A2,
    float* __restrict__ O)
{
  constexpr int L = 2048, H = 16, E = 64, RS = H * E;

  __shared__ __align__(16) char Kb[2 * 16384];   // K region double buffer (128 keys)
  __shared__ __align__(16) char Vb[2 * 16384];   // V^T region double buffer

  const int t = threadIdx.x;
  const int wv = t >> 6;        // wave 0..7
  const int lane = t & 63;
  const int g = lane >> 4;
  const int c = lane & 15;

  const int bh = blockIdx.x;            // x = bh -> XCD-pinned K/V reuse
  const int q0 = blockIdx.y * 128;
  const int b = bh >> 4;
  const int h = bh & 15;

  const float* qb = Q + (size_t)b * L * RS + (size_t)h * E;
  float* ob = O + (size_t)b * L * RS + (size_t)h * E;
  const char* KP = WS;
  const char* VTP = WS + (size_t)8 * 1024 * 1024;

  const float a1 = A1[0], a2 = A2[0];
  const float am = fmaxf(a1, a2);
  const float e1 = expf(a1 - am), e2 = expf(a2 - am);
  const float alpha1 = (e1 / (e1 + e2)) * ILN2SQ;  // relu^2 path: undo LOG2E^2
  const float alpha2 = e2 / (e1 + e2);

  // This wave's 16 q-rows: q0 + wv*16 + c.
  // B-frag layout: lane holds Q[q][e = ks*32 + g*8 + j], pre-scaled by 0.125*LOG2E.
  short8 aq0, aq1;
  {
    const float qs = 0.125f * LOG2E;
    const float* qr = qb + (size_t)(q0 + wv * 16 + c) * RS;
    #pragma unroll
    for (int ks = 0; ks < 2; ++ks) {
      const float4 u0 = *(const float4*)(qr + ks * 32 + g * 8);
      const float4 u1 = *(const float4*)(qr + ks * 32 + g * 8 + 4);
      uint4v w;
      w[0] = packbf2(u0.x * qs, u0.y * qs);
      w[1] = packbf2(u0.z * qs, u0.w * qs);
      w[2] = packbf2(u1.x * qs, u1.y * qs);
      w[3] = packbf2(u1.z * qs, u1.w * qs);
      if (ks) aq1 = __builtin_bit_cast(short8, w);
      else    aq0 = __builtin_bit_cast(short8, w);
    }
  }

  // precomputed swizzled LDS byte offsets (within one 8KB subtile).
  // K-frag and V-frag offsets are identical (same formula); constant +OFS folds
  // into the ds_read offset immediate (do NOT copy into new arrays - r15 spill).
  int ka[8];   // [i16*2+half]: row = i16*16+c; half: +0 / +64
  #pragma unroll
  for (int i16 = 0; i16 < 4; ++i16) {
    const int row = i16 * 16 + c;
    const int s = swz(row);
    ka[i16 * 2 + 0] = (row * 128 + g * 16) ^ s;
    ka[i16 * 2 + 1] = (row * 128 + 64 + g * 16) ^ s;
  }

  const f32x4 ZERO4 = {0.0f, 0.0f, 0.0f, 0.0f};
  f32x4 od[4], os[4];
  #pragma unroll
  for (int i = 0; i < 4; ++i) { od[i] = ZERO4; os[i] = ZERO4; }
  float ps0 = 0.0f, ps1 = 0.0f;

  // staging: 512 threads x 16B = 8KB per gload pass; region = 16KB each for K and V
  const char* kp = KP + (size_t)bh * (2048 * 128) + t * 16;
  const char* vp = VTP + (size_t)bh * (2048 * 128) + t * 16;
  char* kd = Kb + wv * 1024;   // wave-uniform base (lane*16 added by HW)
  char* vd = Vb + wv * 1024;

#define STAGE(TOFF, HALF)                                \
  do {                                                   \
    gload16(kp + (TOFF), kd + (HALF));                   \
    gload16(kp + (TOFF) + 8192, kd + (HALF) + 8192);     \
    gload16(vp + (TOFF), vd + (HALF));                   \
    gload16(vp + (TOFF) + 8192, vd + (HALF) + 8192);     \
  } while (0)

// QK for one 64-key subtile; first MFMA consumes shared ZERO4 (no acc zero-init).
#define QKPART(ACC, OFS)                                                             \
  do {                                                                               \
    _Pragma("unroll")                                                                \
    for (int kt = 0; kt < 4; ++kt) {                                                 \
      const short8 kf0 = *(const short8*)(Kb + ka[kt * 2 + 0] + (OFS));              \
      const short8 kf1 = *(const short8*)(Kb + ka[kt * 2 + 1] + (OFS));              \
      ACC[kt] = __builtin_amdgcn_mfma_f32_16x16x32_bf16(kf0, aq0, ZERO4, 0, 0, 0);   \
      ACC[kt] = __builtin_amdgcn_mfma_f32_16x16x32_bf16(kf1, aq1, ACC[kt], 0, 0, 0); \
    }                                                                                \
  } while (0)

// softmax + PV for one 64-key subtile; scalar math, bit_cast frag builds
// (correctness-proven in r15; r15's slowness was its offset-array copies, not this).
#define SMPV(ACC, OFS)                                                               \
  do {                                                                               \
    _Pragma("unroll")                                                                \
    for (int tp = 0; tp < 2; ++tp) {                                                 \
      const short8 vf0 = *(const short8*)(Vb + ka[0 * 2 + tp] + (OFS));              \
      const short8 vf1 = *(const short8*)(Vb + ka[1 * 2 + tp] + (OFS));              \
      const short8 vf2 = *(const short8*)(Vb + ka[2 * 2 + tp] + (OFS));              \
      const short8 vf3 = *(const short8*)(Vb + ka[3 * 2 + tp] + (OFS));              \
      const float s0 = ACC[tp * 2][0], s1 = ACC[tp * 2][1];                          \
      const float s2 = ACC[tp * 2][2], s3 = ACC[tp * 2][3];                          \
      const float s4 = ACC[tp * 2 + 1][0], s5 = ACC[tp * 2 + 1][1];                  \
      const float s6 = ACC[tp * 2 + 1][2], s7 = ACC[tp * 2 + 1][3];                  \
      const float x0 = __builtin_amdgcn_exp2f(s0);                                   \
      const float x1 = __builtin_amdgcn_exp2f(s1);                                   \
      const float x2 = __builtin_amdgcn_exp2f(s2);                                   \
      const float x3 = __builtin_amdgcn_exp2f(s3);                                   \
      const float x4 = __builtin_amdgcn_exp2f(s4);                                   \
      const float x5 = __builtin_amdgcn_exp2f(s5);                                   \
      const float x6 = __builtin_amdgcn_exp2f(s6);                                   \
      const float x7 = __builtin_amdgcn_exp2f(s7);                                   \
      ps0 += (x0 + x1) + (x2 + x3);                                                  \
      ps1 += (x4 + x5) + (x6 + x7);                                                  \
      const float r0 = fmaxf(s0, 0.0f), r1 = fmaxf(s1, 0.0f);                        \
      const float r2 = fmaxf(s2, 0.0f), r3 = fmaxf(s3, 0.0f);                        \
      const float r4 = fmaxf(s4, 0.0f), r5 = fmaxf(s5, 0.0f);                        \
      const float r6 = fmaxf(s6, 0.0f), r7 = fmaxf(s7, 0.0f);                        \
      uint4v wd, wsq;                                                                \
      wd[0] = packbf2(x0, x1); wd[1] = packbf2(x2, x3);                              \
      wd[2] = packbf2(x4, x5); wd[3] = packbf2(x6, x7);                              \
      wsq[0] = packbf2(r0 * r0, r1 * r1); wsq[1] = packbf2(r2 * r2, r3 * r3);        \
      wsq[2] = packbf2(r4 * r4, r5 * r5); wsq[3] = packbf2(r6 * r6, r7 * r7);        \
      const short8 bpd = __builtin_bit_cast(short8, wd);                             \
      const short8 bps = __builtin_bit_cast(short8, wsq);                            \
      __builtin_amdgcn_s_setprio(1);                                                 \
      od[0] = __builtin_amdgcn_mfma_f32_16x16x32_bf16(vf0, bpd, od[0], 0, 0, 0);     \
      os[0] = __builtin_amdgcn_mfma_f32_16x16x32_bf16(vf0, bps, os[0], 0, 0, 0);     \
      od[1] = __builtin_amdgcn_mfma_f32_16x16x32_bf16(vf1, bpd, od[1], 0, 0, 0);     \
      os[1] = __builtin_amdgcn_mfma_f32_16x16x32_bf16(vf1, bps, os[1], 0, 0, 0);     \
      od[2] = __builtin_amdgcn_mfma_f32_16x16x32_bf16(vf2, bpd, od[2], 0, 0, 0);     \
      os[2] = __builtin_amdgcn_mfma_f32_16x16x32_bf16(vf2, bps, os[2], 0, 0, 0);     \
      od[3] = __builtin_amdgcn_mfma_f32_16x16x32_bf16(vf3, bpd, od[3], 0, 0, 0);     \
      os[3] = __builtin_amdgcn_mfma_f32_16x16x32_bf16(vf3, bps, os[3], 0, 0, 0);     \
      __builtin_amdgcn_s_setprio(0);                                                 \
    }                                                                                \
  } while (0)

#define SUBTILE(SOFF)                                    \
  do {                                                   \
    f32x4 acc[4];                                        \
    QKPART(acc, SOFF);                                   \
    SMPV(acc, SOFF);                                     \
  } while (0)

  STAGE(0, 0);
  __syncthreads();
  int toff = 16384;
  for (int r = 0; r < 16; ++r) {
    if (r + 1 < 16) { STAGE(toff, ((r + 1) & 1) * 16384); toff += 16384; }
    const int OFS = (r & 1) * 16384;
    SUBTILE(OFS);
    SUBTILE(OFS + 8192);
    __syncthreads();
  }
#undef STAGE
#undef QKPART
#undef SMPV
#undef SUBTILE

  // ---- final l reduction (per q-row = c, across 4 lane groups) ----
  float l = ps0 + ps1;
  l += __shfl_xor(l, 16);
  l += __shfl_xor(l, 32);

  // ---- epilogue: out[q][e=et*16+g*4+r] ----
  const float wd = alpha2 / l;
  float* orow = ob + (size_t)(q0 + wv * 16 + c) * RS;
  #pragma unroll
  for (int et = 0; et < 4; ++et) {
    float4 o;
    o.x = alpha1 * os[et][0] + wd * od[et][0];
    o.y = alpha1 * os[et][1] + wd * od[et][1];
    o.z = alpha1 * os[et][2] + wd * od[et][2];
    o.w = alpha1 * os[et][3] + wd * od[et][3];
    *(float4*)(orow + et * 16 + g * 4) = o;
  }
}

extern "C" void kernel_launch(void* const* d_in, const int* in_sizes, int n_in,
                              void* d_out, int out_size, void* d_ws, size_t ws_size,
                              hipStream_t stream) {
  const float* q = (const float*)d_in[0];
  const float* k = (const float*)d_in[1];
  const float* v = (const float*)d_in[2];
  const float* a1 = (const float*)d_in[3];
  const float* a2 = (const float*)d_in[4];
  float* out = (float*)d_out;
  char* ws = (char*)d_ws;

  assa_prep<<<2048, 256, 0, stream>>>(k, v, ws);
  dim3 grid(32, 16);  // x = bh (XCD-pinned), y = q-tile of 128 rows
  assa_fused<<<grid, 512, 0, stream>>>(q, ws, a1, a2, out);
}

// Round 20
// 80.185 us; speedup vs baseline: 1.9853x; 1.9853x over previous
//
#include <hip/hip_runtime.h>
#include <hip/hip_bf16.h>

typedef __attribute__((ext_vector_type(8))) short short8;
typedef __attribute__((ext_vector_type(4))) float f32x4;
typedef __attribute__((ext_vector_type(2))) float f32x2;
typedef __attribute__((ext_vector_type(4))) unsigned uint4v;

#define LOG2E 1.4426950408889634f
#define ILN2SQ 0.4804530139182014f   // (ln2)^2, compensates LOG2E^2 in relu^2 path

// compiler emits v_cvt_pk_bf16_f32 for this (m240: do NOT hand-write the asm)
__device__ __forceinline__ unsigned packbf2(float a, float b) {
  __hip_bfloat162 h = __float22bfloat162_rn(make_float2(a, b));
  return *reinterpret_cast<unsigned*>(&h);
}
// XOR swizzle spreading 16B chunks across banks; bits 4..6 only (within 128B row)
__device__ __forceinline__ int swz(int row) {
  return ((row & 7) << 4) ^ (((row >> 3) & 3) << 5);
}
__device__ __forceinline__ void gload16(const void* g, void* l) {
  __builtin_amdgcn_global_load_lds(
      (const __attribute__((address_space(1))) unsigned int*)g,
      (__attribute__((address_space(3))) unsigned int*)l, 16, 0, 0);
}

// PV key permutation: logical slot p (0..63) within a V^T row maps to physical key
//   R = p>>5, g = (p&31)>>3, jj = p&7  ->  key = (R*2 + (jj>>2))*16 + g*4 + (jj&3)
// so that lane-group g's 16B fragment read delivers keys matching the lane's own
// QK^T accumulator scores (B-frag = concat of packed acc, no shuffles).
__device__ __forceinline__ int pv_key(int p) {
  const int R = p >> 5, g = (p & 31) >> 3, jj = p & 7;
  return (R * 2 + (jj >> 2)) * 16 + g * 4 + (jj & 3);
}

// ---------------- prep: fp32 -> bf16, pre-swizzled global layouts ----------------
// KP  = ws[0..8MB):   [bh][s][128B]      bf16 K rows, 16B chunks XOR-swz by s
// VTP = ws[8MB..16MB): [bh][t][e][128B]  bf16 V^T tiles, PV-KEY-PERMUTED within row
//        (byte pos 2*p holds V[pv_key(p)][e]); XOR-swz by e.
__global__ __launch_bounds__(256) void assa_prep(
    const float* __restrict__ K, const float* __restrict__ V, char* __restrict__ WS)
{
  constexpr int L = 2048, RS = 1024, E = 64;
  char* KP = WS;
  char* VTP = WS + (size_t)8 * 1024 * 1024;
  __shared__ float tile[64][65];
  const int tid = threadIdx.x;

  if (blockIdx.x < 1024) {
    // ---- K path: thread = quarter row (16 floats) ----
    const int gid = blockIdx.x * 256 + tid;
    const int rid = gid >> 2;            // bh*2048 + s
    const int e0 = (gid & 3) * 16;
    const int bh = rid >> 11, s = rid & 2047;
    const int b = bh >> 4, h = bh & 15;
    const float* kr = K + ((size_t)b * L + s) * RS + h * E + e0;
    const float4 u0 = *(const float4*)(kr);
    const float4 u1 = *(const float4*)(kr + 4);
    const float4 u2 = *(const float4*)(kr + 8);
    const float4 u3 = *(const float4*)(kr + 12);
    uint4v w0, w1;
    w0[0] = packbf2(u0.x, u0.y); w0[1] = packbf2(u0.z, u0.w);
    w0[2] = packbf2(u1.x, u1.y); w0[3] = packbf2(u1.z, u1.w);
    w1[0] = packbf2(u2.x, u2.y); w1[1] = packbf2(u2.z, u2.w);
    w1[2] = packbf2(u3.x, u3.y); w1[3] = packbf2(u3.z, u3.w);
    char* dst = KP + (size_t)rid * 128;
    const int sz = swz(s);
    *(uint4v*)(dst + ((e0 * 2) ^ sz)) = w0;
    *(uint4v*)(dst + ((e0 * 2 + 16) ^ sz)) = w1;
  } else {
    // ---- V path: block = (bh, t); transpose 64x64 via LDS, pv_key-permuted write ----
    const int bx = blockIdx.x - 1024;
    const int bh = bx >> 5, t5 = bx & 31;
    const int b = bh >> 4, h = bh & 15;
    const float* vb = V + ((size_t)b * L + t5 * 64) * RS + h * E;
    {
      const int key = tid >> 2, e0 = (tid & 3) * 16;
      const float* vr = vb + (size_t)key * RS + e0;
      const float4 u0 = *(const float4*)(vr);
      const float4 u1 = *(const float4*)(vr + 4);
      const float4 u2 = *(const float4*)(vr + 8);
      const float4 u3 = *(const float4*)(vr + 12);
      float* tr = &tile[key][e0];
      tr[0] = u0.x; tr[1] = u0.y; tr[2] = u0.z; tr[3] = u0.w;
      tr[4] = u1.x; tr[5] = u1.y; tr[6] = u1.z; tr[7] = u1.w;
      tr[8] = u2.x; tr[9] = u2.y; tr[10] = u2.z; tr[11] = u2.w;
      tr[12] = u3.x; tr[13] = u3.y; tr[14] = u3.z; tr[15] = u3.w;
    }
    __syncthreads();
    const int e = tid >> 2, p0 = (tid & 3) * 16;   // positions p0..p0+15
    uint4v w0, w1;
    #pragma unroll
    for (int i = 0; i < 4; ++i)
      w0[i] = packbf2(tile[pv_key(p0 + 2 * i)][e], tile[pv_key(p0 + 2 * i + 1)][e]);
    #pragma unroll
    for (int i = 0; i < 4; ++i)
      w1[i] = packbf2(tile[pv_key(p0 + 8 + 2 * i)][e], tile[pv_key(p0 + 9 + 2 * i)][e]);
    char* dst = VTP + ((size_t)bx * 64 + e) * 128;
    const int sz = swz(e);
    *(uint4v*)(dst + ((p0 * 2) ^ sz)) = w0;
    *(uint4v*)(dst + ((p0 * 2 + 16) ^ sz)) = w1;
  }
}

// -------- main fused: QBLK=128, 8 waves x 16 q-rows, KVBLK=128 (2 subtiles) --------
// launch_bounds(512,2): LDS already limits to 2 blocks/CU (4 waves/SIMD); declaring
// 2 waves/SIMD doubles the arch-VGPR budget so the allocator stops AGPR-shuttling.
__global__ __launch_bounds__(512, 2) void assa_fused(
    const float* __restrict__ Q, const char* __restrict__ WS,
    const float* __restrict__ A1, const float* __restrict__ A2,
    float* __restrict__ O)
{
  constexpr int L = 2048, H = 16, E = 64, RS = H * E;

  __shared__ __align__(16) char Kb[2 * 16384];   // K region double buffer (128 keys)
  __shared__ __align__(16) char Vb[2 * 16384];   // V^T region double buffer

  const int t = threadIdx.x;
  const int wv = t >> 6;        // wave 0..7
  const int lane = t & 63;
  const int g = lane >> 4;
  const int c = lane & 15;

  const int bh = blockIdx.x;            // x = bh -> XCD-pinned K/V reuse
  const int q0 = blockIdx.y * 128;
  const int b = bh >> 4;
  const int h = bh & 15;

  const float* qb = Q + (size_t)b * L * RS + (size_t)h * E;
  float* ob = O + (size_t)b * L * RS + (size_t)h * E;
  const char* KP = WS;
  const char* VTP = WS + (size_t)8 * 1024 * 1024;

  const float a1 = A1[0], a2 = A2[0];
  const float am = fmaxf(a1, a2);
  const float e1 = expf(a1 - am), e2 = expf(a2 - am);
  const float alpha1 = (e1 / (e1 + e2)) * ILN2SQ;  // relu^2 path: undo LOG2E^2
  const float alpha2 = e2 / (e1 + e2);

  // This wave's 16 q-rows: q0 + wv*16 + c.
  // B-frag layout: lane holds Q[q][e = ks*32 + g*8 + j], pre-scaled by 0.125*LOG2E.
  short8 aq[2];
  {
    const float qs = 0.125f * LOG2E;
    const float* qr = qb + (size_t)(q0 + wv * 16 + c) * RS;
    #pragma unroll
    for (int ks = 0; ks < 2; ++ks) {
      const float4 u0 = *(const float4*)(qr + ks * 32 + g * 8);
      const float4 u1 = *(const float4*)(qr + ks * 32 + g * 8 + 4);
      union { unsigned u[4]; short8 s; } f;
      f.u[0] = packbf2(u0.x * qs, u0.y * qs);
      f.u[1] = packbf2(u0.z * qs, u0.w * qs);
      f.u[2] = packbf2(u1.x * qs, u1.y * qs);
      f.u[3] = packbf2(u1.z * qs, u1.w * qs);
      aq[ks] = f.s;
    }
  }

  // precomputed swizzled LDS byte offsets (within one 8KB subtile).
  // K-frag and V-frag offsets are identical (same formula); constant +OFS folds
  // into the ds_read offset immediate (do NOT copy into new arrays - r15 spill).
  int ka[8];   // [i16*2+half]: row = i16*16+c; half: +0 / +64
  #pragma unroll
  for (int i16 = 0; i16 < 4; ++i16) {
    const int row = i16 * 16 + c;
    const int s = swz(row);
    ka[i16 * 2 + 0] = (row * 128 + g * 16) ^ s;
    ka[i16 * 2 + 1] = (row * 128 + 64 + g * 16) ^ s;
  }

  const f32x4 zero4 = {0.0f, 0.0f, 0.0f, 0.0f};
  f32x4 od[4], os[4];
  #pragma unroll
  for (int i = 0; i < 4; ++i) { od[i] = zero4; os[i] = zero4; }
  f32x2 psa = {0.0f, 0.0f}, psb = {0.0f, 0.0f};

  // staging: 512 threads x 16B = 8KB per gload pass; region = 16KB each for K and V
  const char* kp = KP + (size_t)bh * (2048 * 128) + t * 16;
  const char* vp = VTP + (size_t)bh * (2048 * 128) + t * 16;
  char* kd = Kb + wv * 1024;   // wave-uniform base (lane*16 added by HW)
  char* vd = Vb + wv * 1024;

  union U8 { unsigned u[4]; short8 s; };

#define STAGE(TOFF, HALF)                                \
  do {                                                   \
    gload16(kp + (TOFF), kd + (HALF));                   \
    gload16(kp + (TOFF) + 8192, kd + (HALF) + 8192);     \
    gload16(vp + (TOFF), vd + (HALF));                   \
    gload16(vp + (TOFF) + 8192, vd + (HALF) + 8192);     \
  } while (0)

#define QKPART(ACC, OFS)                                                             \
  do {                                                                               \
    _Pragma("unroll")                                                                \
    for (int kt = 0; kt < 4; ++kt) {                                                 \
      const short8 kf0 = *(const short8*)(Kb + ka[kt * 2 + 0] + (OFS));              \
      const short8 kf1 = *(const short8*)(Kb + ka[kt * 2 + 1] + (OFS));              \
      ACC[kt] = __builtin_amdgcn_mfma_f32_16x16x32_bf16(kf0, aq[0], ACC[kt], 0, 0, 0);\
      ACC[kt] = __builtin_amdgcn_mfma_f32_16x16x32_bf16(kf1, aq[1], ACC[kt], 0, 0, 0);\
    }                                                                                \
  } while (0)

// per-tp slim softmax+PV: 4 V-frag loads, pk-math SM, 8 MFMAs.
#define SMPV(ACC, OFS)                                                               \
  do {                                                                               \
    _Pragma("unroll")                                                                \
    for (int tp = 0; tp < 2; ++tp) {                                                 \
      short8 vfA0 = *(const short8*)(Vb + ka[0 * 2 + tp] + (OFS));                   \
      short8 vfA1 = *(const short8*)(Vb + ka[1 * 2 + tp] + (OFS));                   \
      short8 vfA2 = *(const short8*)(Vb + ka[2 * 2 + tp] + (OFS));                   \
      short8 vfA3 = *(const short8*)(Vb + ka[3 * 2 + tp] + (OFS));                   \
      const f32x4 a0 = ACC[tp * 2], a1 = ACC[tp * 2 + 1];                            \
      const float x00 = __builtin_amdgcn_exp2f(a0[0]);                               \
      const float x01 = __builtin_amdgcn_exp2f(a0[1]);                               \
      const float x02 = __builtin_amdgcn_exp2f(a0[2]);                               \
      const float x03 = __builtin_amdgcn_exp2f(a0[3]);                               \
      const float x10 = __builtin_amdgcn_exp2f(a1[0]);                               \
      const float x11 = __builtin_amdgcn_exp2f(a1[1]);                               \
      const float x12 = __builtin_amdgcn_exp2f(a1[2]);                               \
      const float x13 = __builtin_amdgcn_exp2f(a1[3]);                               \
      psa += (f32x2){x00, x01}; psb += (f32x2){x02, x03};                            \
      psa += (f32x2){x10, x11}; psb += (f32x2){x12, x13};                            \
      f32x2 r00 = {a0[0], a0[1]}, r01 = {a0[2], a0[3]};                              \
      f32x2 r10 = {a1[0], a1[1]}, r11 = {a1[2], a1[3]};                              \
      const f32x2 z2 = {0.0f, 0.0f};                                                 \
      r00 = __builtin_elementwise_max(r00, z2); r00 *= r00;                          \
      r01 = __builtin_elementwise_max(r01, z2); r01 *= r01;                          \
      r10 = __builtin_elementwise_max(r10, z2); r10 *= r10;                          \
      r11 = __builtin_elementwise_max(r11, z2); r11 *= r11;                          \
      U8 bpd, bps;                                                                   \
      bpd.u[0] = packbf2(x00, x01); bpd.u[1] = packbf2(x02, x03);                    \
      bpd.u[2] = packbf2(x10, x11); bpd.u[3] = packbf2(x12, x13);                    \
      bps.u[0] = packbf2(r00[0], r00[1]); bps.u[1] = packbf2(r01[0], r01[1]);        \
      bps.u[2] = packbf2(r10[0], r10[1]); bps.u[3] = packbf2(r11[0], r11[1]);        \
      __builtin_amdgcn_s_setprio(1);                                                 \
      od[0] = __builtin_amdgcn_mfma_f32_16x16x32_bf16(vfA0, bpd.s, od[0], 0, 0, 0);  \
      os[0] = __builtin_amdgcn_mfma_f32_16x16x32_bf16(vfA0, bps.s, os[0], 0, 0, 0);  \
      od[1] = __builtin_amdgcn_mfma_f32_16x16x32_bf16(vfA1, bpd.s, od[1], 0, 0, 0);  \
      os[1] = __builtin_amdgcn_mfma_f32_16x16x32_bf16(vfA1, bps.s, os[1], 0, 0, 0);  \
      od[2] = __builtin_amdgcn_mfma_f32_16x16x32_bf16(vfA2, bpd.s, od[2], 0, 0, 0);  \
      os[2] = __builtin_amdgcn_mfma_f32_16x16x32_bf16(vfA2, bps.s, os[2], 0, 0, 0);  \
      od[3] = __builtin_amdgcn_mfma_f32_16x16x32_bf16(vfA3, bpd.s, od[3], 0, 0, 0);  \
      os[3] = __builtin_amdgcn_mfma_f32_16x16x32_bf16(vfA3, bps.s, os[3], 0, 0, 0);  \
      __builtin_amdgcn_s_setprio(0);                                                 \
    }                                                                                \
  } while (0)

#define SUBTILE(SOFF)                                    \
  do {                                                   \
    f32x4 acc[4];                                        \
    _Pragma("unroll")                                    \
    for (int i = 0; i < 4; ++i) acc[i] = zero4;          \
    QKPART(acc, SOFF);                                   \
    SMPV(acc, SOFF);                                     \
  } while (0)

  STAGE(0, 0);
  __syncthreads();
  int toff = 16384;
  for (int r = 0; r < 16; ++r) {
    if (r + 1 < 16) { STAGE(toff, ((r + 1) & 1) * 16384); toff += 16384; }
    const int OFS = (r & 1) * 16384;
    SUBTILE(OFS);
    SUBTILE(OFS + 8192);
    __syncthreads();
  }
#undef STAGE
#undef QKPART
#undef SMPV
#undef SUBTILE

  // ---- final l reduction (per q-row = c, across 4 lane groups) ----
  const f32x2 lv = psa + psb;
  float l = lv[0] + lv[1];
  l += __shfl_xor(l, 16);
  l += __shfl_xor(l, 32);

  // ---- epilogue: out[q][e=et*16+g*4+r] ----
  const float wd = alpha2 / l;
  float* orow = ob + (size_t)(q0 + wv * 16 + c) * RS;
  #pragma unroll
  for (int et = 0; et < 4; ++et) {
    float4 o;
    o.x = alpha1 * os[et][0] + wd * od[et][0];
    o.y = alpha1 * os[et][1] + wd * od[et][1];
    o.z = alpha1 * os[et][2] + wd * od[et][2];
    o.w = alpha1 * os[et][3] + wd * od[et][3];
    *(float4*)(orow + et * 16 + g * 4) = o;
  }
}

extern "C" void kernel_launch(void* const* d_in, const int* in_sizes, int n_in,
                              void* d_out, int out_size, void* d_ws, size_t ws_size,
                              hipStream_t stream) {
  const float* q = (const float*)d_in[0];
  const float* k = (const float*)d_in[1];
  const float* v = (const float*)d_in[2];
  const float* a1 = (const float*)d_in[3];
  const float* a2 = (const float*)d_in[4];
  float* out = (float*)d_out;
  char* ws = (char*)d_ws;

  assa_prep<<<2048, 256, 0, stream>>>(k, v, ws);
  dim3 grid(32, 16);  // x = bh (XCD-pinned), y = q-tile of 128 rows
  assa_fused<<<grid, 512, 0, stream>>>(q, ws, a1, a2, out);
}

// Round 22
// 78.804 us; speedup vs baseline: 2.0201x; 1.0175x over previous
//
#include <hip/hip_runtime.h>
#include <hip/hip_bf16.h>

typedef __attribute__((ext_vector_type(8))) short short8;
typedef __attribute__((ext_vector_type(16))) float f32x16;
typedef __attribute__((ext_vector_type(2))) float f32x2;
typedef __attribute__((ext_vector_type(4))) unsigned uint4v;

#define LOG2E 1.4426950408889634f
#define ILN2SQ 0.4804530139182014f   // (ln2)^2, compensates LOG2E^2 in relu^2 path

__device__ __forceinline__ unsigned packbf2(float a, float b) {
  __hip_bfloat162 h = __float22bfloat162_rn(make_float2(a, b));
  return *reinterpret_cast<unsigned*>(&h);
}
// XOR swizzle spreading 16B chunks across banks; bits 4..6 only (within 128B row)
__device__ __forceinline__ int swz(int row) {
  return ((row & 7) << 4) ^ (((row >> 3) & 3) << 5);
}
__device__ __forceinline__ void gload16(const void* g, void* l) {
  __builtin_amdgcn_global_load_lds(
      (const __attribute__((address_space(1))) unsigned int*)g,
      (__attribute__((address_space(3))) unsigned int*)l, 16, 0, 0);
}

// PV key permutation for the 32x32x16 path. Logical byte-position p (0..63) in a
// V^T row maps to physical key so the PV B-fragment (slice s, lane-half h, idx)
// is exactly the lane's own QK^T acc regs 8*sigma..8*sigma+7:
//   s=p>>4, T=s>>1, sigma=s&1, h=(p&15)>>3, idx=p&7
//   key = 32T + 16*sigma + 4h + (idx<4 ? idx : idx+4)
__device__ __forceinline__ int pv_key32(int p) {
  const int s = p >> 4, T = s >> 1, sg = s & 1;
  const int h = (p & 15) >> 3, idx = p & 7;
  return 32 * T + 16 * sg + 4 * h + (idx < 4 ? idx : idx + 4);
}

// ---------------- prep: fp32 -> bf16, pre-swizzled global layouts ----------------
// KP  = ws[0..8MB):   [bh][s][128B]      bf16 K rows, 16B chunks XOR-swz by s
// VTP = ws[8MB..16MB): [bh][t][e][128B]  bf16 V^T tiles, pv_key32-PERMUTED within
//        row (byte pos 2*p holds V[pv_key32(p)][e]); XOR-swz by e.
__global__ __launch_bounds__(256) void assa_prep(
    const float* __restrict__ K, const float* __restrict__ V, char* __restrict__ WS)
{
  constexpr int L = 2048, RS = 1024, E = 64;
  char* KP = WS;
  char* VTP = WS + (size_t)8 * 1024 * 1024;
  __shared__ float tile[64][65];
  const int tid = threadIdx.x;

  if (blockIdx.x < 1024) {
    // ---- K path: thread = quarter row (16 floats) ----
    const int gid = blockIdx.x * 256 + tid;
    const int rid = gid >> 2;            // bh*2048 + s
    const int e0 = (gid & 3) * 16;
    const int bh = rid >> 11, s = rid & 2047;
    const int b = bh >> 4, h = bh & 15;
    const float* kr = K + ((size_t)b * L + s) * RS + h * E + e0;
    const float4 u0 = *(const float4*)(kr);
    const float4 u1 = *(const float4*)(kr + 4);
    const float4 u2 = *(const float4*)(kr + 8);
    const float4 u3 = *(const float4*)(kr + 12);
    uint4v w0, w1;
    w0[0] = packbf2(u0.x, u0.y); w0[1] = packbf2(u0.z, u0.w);
    w0[2] = packbf2(u1.x, u1.y); w0[3] = packbf2(u1.z, u1.w);
    w1[0] = packbf2(u2.x, u2.y); w1[1] = packbf2(u2.z, u2.w);
    w1[2] = packbf2(u3.x, u3.y); w1[3] = packbf2(u3.z, u3.w);
    char* dst = KP + (size_t)rid * 128;
    const int sz = swz(s);
    *(uint4v*)(dst + ((e0 * 2) ^ sz)) = w0;
    *(uint4v*)(dst + ((e0 * 2 + 16) ^ sz)) = w1;
  } else {
    // ---- V path: block = (bh, t); transpose 64x64 via LDS, pv_key32 write ----
    const int bx = blockIdx.x - 1024;
    const int bh = bx >> 5, t5 = bx & 31;
    const int b = bh >> 4, h = bh & 15;
    const float* vb = V + ((size_t)b * L + t5 * 64) * RS + h * E;
    {
      const int key = tid >> 2, e0 = (tid & 3) * 16;
      const float* vr = vb + (size_t)key * RS + e0;
      const float4 u0 = *(const float4*)(vr);
      const float4 u1 = *(const float4*)(vr + 4);
      const float4 u2 = *(const float4*)(vr + 8);
      const float4 u3 = *(const float4*)(vr + 12);
      float* tr = &tile[key][e0];
      tr[0] = u0.x; tr[1] = u0.y; tr[2] = u0.z; tr[3] = u0.w;
      tr[4] = u1.x; tr[5] = u1.y; tr[6] = u1.z; tr[7] = u1.w;
      tr[8] = u2.x; tr[9] = u2.y; tr[10] = u2.z; tr[11] = u2.w;
      tr[12] = u3.x; tr[13] = u3.y; tr[14] = u3.z; tr[15] = u3.w;
    }
    __syncthreads();
    const int e = tid >> 2, p0 = (tid & 3) * 16;   // positions p0..p0+15
    uint4v w0, w1;
    #pragma unroll
    for (int i = 0; i < 4; ++i)
      w0[i] = packbf2(tile[pv_key32(p0 + 2 * i)][e], tile[pv_key32(p0 + 2 * i + 1)][e]);
    #pragma unroll
    for (int i = 0; i < 4; ++i)
      w1[i] = packbf2(tile[pv_key32(p0 + 8 + 2 * i)][e], tile[pv_key32(p0 + 9 + 2 * i)][e]);
    char* dst = VTP + ((size_t)bx * 64 + e) * 128;
    const int sz = swz(e);
    *(uint4v*)(dst + ((p0 * 2) ^ sz)) = w0;
    *(uint4v*)(dst + ((p0 * 2 + 16) ^ sz)) = w1;
  }
}

// ---- main fused: 32x32x16 MFMA; QBLK=128 = 4 waves x 32 q; KVBLK=128 regions ----
__global__ __launch_bounds__(256, 2) void assa_fused(
    const float* __restrict__ Q, const char* __restrict__ WS,
    const float* __restrict__ A1, const float* __restrict__ A2,
    float* __restrict__ O)
{
  constexpr int L = 2048, H = 16, E = 64, RS = H * E;

  __shared__ __align__(16) char Kb[2 * 16384];   // K region double buffer (128 keys)
  __shared__ __align__(16) char Vb[2 * 16384];   // V^T region double buffer

  const int t = threadIdx.x;
  const int wv = t >> 6;        // wave 0..3
  const int lane = t & 63;
  const int cq = lane & 31;     // this lane's q-column (and K/V row index)
  const int h = lane >> 5;      // lane half

  const int bh = blockIdx.x;            // x = bh -> XCD-pinned K/V reuse
  const int q0 = blockIdx.y * 128;
  const int b = bh >> 4;
  const int hh = bh & 15;

  const float* qb = Q + (size_t)b * L * RS + (size_t)hh * E;
  float* ob = O + (size_t)b * L * RS + (size_t)hh * E;
  const char* KP = WS;
  const char* VTP = WS + (size_t)8 * 1024 * 1024;

  const float a1 = A1[0], a2 = A2[0];
  const float am = fmaxf(a1, a2);
  const float e1 = expf(a1 - am), e2 = expf(a2 - am);
  const float alpha1 = (e1 / (e1 + e2)) * ILN2SQ;  // relu^2 path: undo LOG2E^2
  const float alpha2 = e2 / (e1 + e2);

  // Q fragments (B operand of QK, 32x32x16): lane holds Q[q=cq][e=16*kk+8*h+j],
  // pre-scaled by 0.125*LOG2E. 4 slices kk over K(=e)=64.
  short8 aq[4];
  {
    const float qs = 0.125f * LOG2E;
    const float* qr = qb + (size_t)(q0 + wv * 32 + cq) * RS;
    #pragma unroll
    for (int kk = 0; kk < 4; ++kk) {
      const float4 u0 = *(const float4*)(qr + kk * 16 + h * 8);
      const float4 u1 = *(const float4*)(qr + kk * 16 + h * 8 + 4);
      union { unsigned u[4]; short8 s; } f;
      f.u[0] = packbf2(u0.x * qs, u0.y * qs);
      f.u[1] = packbf2(u0.z * qs, u0.w * qs);
      f.u[2] = packbf2(u1.x * qs, u1.y * qs);
      f.u[3] = packbf2(u1.z * qs, u1.w * qs);
      aq[kk] = f.s;
    }
  }

  // Swizzled LDS offsets within one 8KB (64-row) subtile. Row-tile i (0..1),
  // column-slice j (0..3): row = i*32+cq, 16B chunk at ((32j + 16h) ^ swz(row)).
  // Serves BOTH K-frag (i=T, j=e-slice) and V^T-frag (i=E, j=key-slice).
  int ka[8];
  #pragma unroll
  for (int i = 0; i < 2; ++i) {
    const int row = i * 32 + cq;
    const int s = swz(row);
    #pragma unroll
    for (int j = 0; j < 4; ++j)
      ka[i * 4 + j] = row * 128 + ((32 * j + 16 * h) ^ s);
  }

  f32x16 od0, od1, os0, os1;
  #pragma unroll
  for (int i = 0; i < 16; ++i) { od0[i] = 0.0f; od1[i] = 0.0f; os0[i] = 0.0f; os1[i] = 0.0f; }
  f32x2 psa = {0.0f, 0.0f}, psb = {0.0f, 0.0f};

  // staging: 256 threads x 16B = 4KB per gload pass; 4 passes per 16KB region each
  const char* kp = KP + (size_t)bh * (2048 * 128) + t * 16;
  const char* vp = VTP + (size_t)bh * (2048 * 128) + t * 16;
  char* kd = Kb + wv * 1024;   // wave-uniform base (lane*16 added by HW)
  char* vd = Vb + wv * 1024;

  union U8 { unsigned u[4]; short8 s; };

#define STAGE(TOFF, HALF)                                        \
  do {                                                           \
    _Pragma("unroll")                                            \
    for (int j = 0; j < 4; ++j) {                                \
      gload16(kp + (TOFF) + j * 4096, kd + (HALF) + j * 4096);   \
      gload16(vp + (TOFF) + j * 4096, vd + (HALF) + j * 4096);   \
    }                                                            \
  } while (0)

// One softmax+PV slice: scores = ACCT regs 8*SG..8*SG+7; V^T frags at ka[E*4+S].
#define SLICE(ACCT, SG, S, OFS)                                                      \
  do {                                                                               \
    const short8 vf0 = *(const short8*)(Vb + ka[0 * 4 + (S)] + (OFS));               \
    const short8 vf1 = *(const short8*)(Vb + ka[1 * 4 + (S)] + (OFS));               \
    const float x0 = __builtin_amdgcn_exp2f(ACCT[8 * (SG) + 0]);                     \
    const float x1 = __builtin_amdgcn_exp2f(ACCT[8 * (SG) + 1]);                     \
    const float x2 = __builtin_amdgcn_exp2f(ACCT[8 * (SG) + 2]);                     \
    const float x3 = __builtin_amdgcn_exp2f(ACCT[8 * (SG) + 3]);                     \
    const float x4 = __builtin_amdgcn_exp2f(ACCT[8 * (SG) + 4]);                     \
    const float x5 = __builtin_amdgcn_exp2f(ACCT[8 * (SG) + 5]);                     \
    const float x6 = __builtin_amdgcn_exp2f(ACCT[8 * (SG) + 6]);                     \
    const float x7 = __builtin_amdgcn_exp2f(ACCT[8 * (SG) + 7]);                     \
    psa += (f32x2){x0, x1}; psb += (f32x2){x2, x3};                                  \
    psa += (f32x2){x4, x5}; psb += (f32x2){x6, x7};                                  \
    f32x2 r0 = {ACCT[8 * (SG) + 0], ACCT[8 * (SG) + 1]};                             \
    f32x2 r1 = {ACCT[8 * (SG) + 2], ACCT[8 * (SG) + 3]};                             \
    f32x2 r2 = {ACCT[8 * (SG) + 4], ACCT[8 * (SG) + 5]};                             \
    f32x2 r3 = {ACCT[8 * (SG) + 6], ACCT[8 * (SG) + 7]};                             \
    const f32x2 z2 = {0.0f, 0.0f};                                                   \
    r0 = __builtin_elementwise_max(r0, z2); r0 *= r0;                                \
    r1 = __builtin_elementwise_max(r1, z2); r1 *= r1;                                \
    r2 = __builtin_elementwise_max(r2, z2); r2 *= r2;                                \
    r3 = __builtin_elementwise_max(r3, z2); r3 *= r3;                                \
    U8 bpd, bps;                                                                     \
    bpd.u[0] = packbf2(x0, x1); bpd.u[1] = packbf2(x2, x3);                          \
    bpd.u[2] = packbf2(x4, x5); bpd.u[3] = packbf2(x6, x7);                          \
    bps.u[0] = packbf2(r0[0], r0[1]); bps.u[1] = packbf2(r1[0], r1[1]);              \
    bps.u[2] = packbf2(r2[0], r2[1]); bps.u[3] = packbf2(r3[0], r3[1]);              \
    __builtin_amdgcn_s_setprio(1);                                                   \
    od0 = __builtin_amdgcn_mfma_f32_32x32x16_bf16(vf0, bpd.s, od0, 0, 0, 0);         \
    os0 = __builtin_amdgcn_mfma_f32_32x32x16_bf16(vf0, bps.s, os0, 0, 0, 0);         \
    od1 = __builtin_amdgcn_mfma_f32_32x32x16_bf16(vf1, bpd.s, od1, 0, 0, 0);         \
    os1 = __builtin_amdgcn_mfma_f32_32x32x16_bf16(vf1, bps.s, os1, 0, 0, 0);         \
    __builtin_amdgcn_s_setprio(0);                                                   \
  } while (0)

#define SUBTILE(OFS)                                                                 \
  do {                                                                               \
    f32x16 acc0, acc1;                                                               \
    _Pragma("unroll")                                                                \
    for (int i = 0; i < 16; ++i) { acc0[i] = 0.0f; acc1[i] = 0.0f; }                 \
    _Pragma("unroll")                                                                \
    for (int kk = 0; kk < 4; ++kk) {                                                 \
      const short8 kf0 = *(const short8*)(Kb + ka[0 * 4 + kk] + (OFS));              \
      const short8 kf1 = *(const short8*)(Kb + ka[1 * 4 + kk] + (OFS));              \
      acc0 = __builtin_amdgcn_mfma_f32_32x32x16_bf16(kf0, aq[kk], acc0, 0, 0, 0);    \
      acc1 = __builtin_amdgcn_mfma_f32_32x32x16_bf16(kf1, aq[kk], acc1, 0, 0, 0);    \
    }                                                                                \
    SLICE(acc0, 0, 0, OFS);                                                          \
    SLICE(acc0, 1, 1, OFS);                                                          \
    SLICE(acc1, 0, 2, OFS);                                                          \
    SLICE(acc1, 1, 3, OFS);                                                          \
  } while (0)

  STAGE(0, 0);
  __syncthreads();
  int toff = 16384;
  for (int r = 0; r < 16; ++r) {
    if (r + 1 < 16) { STAGE(toff, ((r + 1) & 1) * 16384); toff += 16384; }
    const int OFS = (r & 1) * 16384;
    SUBTILE(OFS);
    SUBTILE(OFS + 8192);
    __syncthreads();
  }
#undef STAGE
#undef SLICE
#undef SUBTILE

  // ---- final l reduction: lane and lane+32 hold the same q ----
  const f32x2 lv = psa + psb;
  float l = lv[0] + lv[1];
  l += __shfl_xor(l, 32);

  // ---- epilogue: out[q=cq][e = E*32 + 8*rq + 4*h + m], regs 4*rq+m ----
  const float wd = alpha2 / l;
  float* orow = ob + (size_t)(q0 + wv * 32 + cq) * RS;
  #pragma unroll
  for (int rq = 0; rq < 4; ++rq) {
    float4 o0, o1;
    o0.x = alpha1 * os0[4 * rq + 0] + wd * od0[4 * rq + 0];
    o0.y = alpha1 * os0[4 * rq + 1] + wd * od0[4 * rq + 1];
    o0.z = alpha1 * os0[4 * rq + 2] + wd * od0[4 * rq + 2];
    o0.w = alpha1 * os0[4 * rq + 3] + wd * od0[4 * rq + 3];
    o1.x = alpha1 * os1[4 * rq + 0] + wd * od1[4 * rq + 0];
    o1.y = alpha1 * os1[4 * rq + 1] + wd * od1[4 * rq + 1];
    o1.z = alpha1 * os1[4 * rq + 2] + wd * od1[4 * rq + 2];
    o1.w = alpha1 * os1[4 * rq + 3] + wd * od1[4 * rq + 3];
    *(float4*)(orow + 8 * rq + 4 * h) = o0;
    *(float4*)(orow + 32 + 8 * rq + 4 * h) = o1;
  }
}

extern "C" void kernel_launch(void* const* d_in, const int* in_sizes, int n_in,
                              void* d_out, int out_size, void* d_ws, size_t ws_size,
                              hipStream_t stream) {
  const float* q = (const float*)d_in[0];
  const float* k = (const float*)d_in[1];
  const float* v = (const float*)d_in[2];
  const float* a1 = (const float*)d_in[3];
  const float* a2 = (const float*)d_in[4];
  float* out = (float*)d_out;
  char* ws = (char*)d_ws;

  assa_prep<<<2048, 256, 0, stream>>>(k, v, ws);
  dim3 grid(32, 16);  // x = bh (XCD-pinned), y = q-tile of 128 rows
  assa_fused<<<grid, 256, 0, stream>>>(q, ws, a1, a2, out);
}